// Round 4
// baseline (227.911 us; speedup 1.0000x reference)
//
#include <hip/hip_runtime.h>

// Problem constants (B=4, H=W=64, C=D=512, heads=8, hd=64, SR=2)
// N = 4096 queries, Nk = 1024 keys.

typedef __attribute__((ext_vector_type(8))) _Float16 f16x8;
typedef __attribute__((ext_vector_type(4))) _Float16 f16x4;
typedef __attribute__((ext_vector_type(4))) float f32x4;

#define EXP2F(x) __builtin_amdgcn_exp2f(x)

// async global->LDS, 16B per lane; LDS dest = wave-uniform base + lane*16
__device__ __forceinline__ void gload_lds16(const _Float16* g, _Float16* l)
{
    __builtin_amdgcn_global_load_lds(
        (const __attribute__((address_space(1))) void*)g,
        (__attribute__((address_space(3))) void*)l, 16, 0, 0);
}

// ---------------------------------------------------------------------------
// Fused prep: blocks [0,4096) x fp32->fp16; [4096,5120) 4x weight transpose;
// [5120,6144) srw transpose. All independent memory-bound work, one launch.
// ---------------------------------------------------------------------------
__global__ __launch_bounds__(256)
void prep_k(const float* __restrict__ x,
            const float* __restrict__ Wq, const float* __restrict__ Wk,
            const float* __restrict__ Wv, const float* __restrict__ Wp,
            const float* __restrict__ srw,
            _Float16* __restrict__ xh, _Float16* __restrict__ wqt,
            _Float16* __restrict__ wkvt, _Float16* __restrict__ wpt,
            _Float16* __restrict__ srwt)
{
    __shared__ float T[32][33];
    const int id = blockIdx.x;
    const int t = threadIdx.x;

    if (id < 4096) {                       // ---- x fp32 -> fp16 ----
        const size_t i = ((size_t)id * 256 + t) * 8;
        const float4 a = *(const float4*)(x + i);
        const float4 b = *(const float4*)(x + i + 4);
        f16x8 o;
        o[0] = (_Float16)a.x; o[1] = (_Float16)a.y; o[2] = (_Float16)a.z; o[3] = (_Float16)a.w;
        o[4] = (_Float16)b.x; o[5] = (_Float16)b.y; o[6] = (_Float16)b.z; o[7] = (_Float16)b.w;
        *(f16x8*)(xh + i) = o;
        return;
    }

    if (id < 5120) {                       // ---- 4x 512x512 transpose ----
        const int id2 = id - 4096;
        const int z = id2 >> 8, k0 = ((id2 >> 4) & 15) * 32, n0 = (id2 & 15) * 32;
        const float* src; _Float16* dst; int perm;
        switch (z) {
            case 0:  src = Wq; dst = wqt;           perm = 1; break;
            case 1:  src = Wk; dst = wkvt;          perm = 1; break;
            case 2:  src = Wv; dst = wkvt + 262144; perm = 0; break;
            default: src = Wp; dst = wpt;           perm = 0; break;
        }
        {
            const int r = t >> 3, c = (t & 7) * 4;
            const float4 v = *(const float4*)(src + (size_t)(k0 + r) * 512 + n0 + c);
            T[r][c + 0] = v.x; T[r][c + 1] = v.y; T[r][c + 2] = v.z; T[r][c + 3] = v.w;
        }
        __syncthreads();
        {
            const int j = t >> 3, i0 = (t & 7) * 4;
            const int n = n0 + j;
            const int nper = perm ? ((n & 7) * 64 + (n >> 3)) : n;
            f16x4 o;
            o[0] = (_Float16)T[i0 + 0][j];
            o[1] = (_Float16)T[i0 + 1][j];
            o[2] = (_Float16)T[i0 + 2][j];
            o[3] = (_Float16)T[i0 + 3][j];
            *(f16x4*)(dst + (size_t)nper * 512 + k0 + i0) = o;
        }
        return;
    }

    {                                      // ---- srw [2048][512] -> [512][2048] ----
        const int id3 = id - 5120;
        const int n0 = (id3 & 15) * 32, k0 = (id3 >> 4) * 32;
        {
            const int r = t >> 3, c = (t & 7) * 4;
            const float4 v = *(const float4*)(srw + (size_t)(k0 + r) * 512 + n0 + c);
            T[r][c + 0] = v.x; T[r][c + 1] = v.y; T[r][c + 2] = v.z; T[r][c + 3] = v.w;
        }
        __syncthreads();
        {
            const int j = t >> 3, i0 = (t & 7) * 4;
            f16x4 o;
            o[0] = (_Float16)T[i0 + 0][j];
            o[1] = (_Float16)T[i0 + 1][j];
            o[2] = (_Float16)T[i0 + 2][j];
            o[3] = (_Float16)T[i0 + 3][j];
            *(f16x4*)(srwt + (size_t)(n0 + j) * 2048 + k0 + i0) = o;
        }
        return;
    }
}

// ---------------------------------------------------------------------------
// fp16 MFMA GEMM body, DOUBLE-BUFFERED 1-barrier-per-K-step pipeline:
//   STAGE(buf^1, t+1) -> ds_read/MFMA from buf -> vmcnt(0) -> s_barrier
// Next tile's global_load_lds are in flight during the whole compute phase
// (latency hidden), vs the old 2-barrier structure that exposed full HBM
// latency every BK=32 step (convq was 45us at 13% MfmaUtil / 8% VALU).
// C[M,128*nx] = A[M,K] @ Wt^T + bias. Wt fp16 [N][K]. BN=128, BK=32.
// 4 waves (2x2): wave tile (BM/2)x64, MT=BM/32 row-tiles x 4 col-tiles.
// As/Ws are 2x-sized (double buffer). LDS = 2*(BM+128)*32*2B.
// MODE: 0 = fp32 row-major [M,512], bias direct
//       4 = fp16 row-major [M,512], bias direct        (conv out)
//       6 = fp16 row-major [M,512], bias head-perm'd    (Q proj)
//       5 = fused KV (N=1024): col<512 -> kh fp16 [4096][512] (perm'd cols);
//           col>=512 -> v^T fp16 [bh][64][1024] batched f16x4 stores
// CONV: A gathered as im2col of 2x2/stride-2 conv on x fp16 (K=2048).
// ---------------------------------------------------------------------------
template<int MODE, bool CONV, int BM>
__device__ __forceinline__ void gemm_body(
    const int bx, const int by,
    const _Float16* __restrict__ A, const _Float16* __restrict__ Wt,
    const float* __restrict__ bias, const float* __restrict__ bias2,
    void* __restrict__ Cv, void* __restrict__ Cv2,
    _Float16* __restrict__ As, _Float16* __restrict__ Ws)
{
    constexpr int K = CONV ? 2048 : 512;
    constexpr int NIT = K / 32;
    constexpr int MT = BM / 32;          // row-tiles per wave
    constexpr int AI = BM / 64;          // A staging instrs per wave
    constexpr int ABUF = BM * 32;        // elems per A buffer
    const int tid = threadIdx.x;
    const int wave = tid >> 6, lane = tid & 63;
    const int quad = lane >> 4, l15 = lane & 15;
    const int wm = wave >> 1, wn = wave & 1;
    const int wrow = wm * (BM / 2);
    const int m0 = by * BM, n0 = bx * 128;

    f32x4 acc[MT][4] = {};

    auto stage = [&](const int k0, const int buf) {
        #pragma unroll
        for (int t = 0; t < AI; ++t) {         // stage A tile
            const int ii = wave * AI + t;
            const int e = ii * 64 + lane;
            const int row = e >> 2, c8 = (e & 3) * 8;
            const _Float16* gp;
            if (CONV) {
                const int grow = m0 + row;
                const int b = grow >> 10, rem = grow & 1023;
                const int oh = rem >> 5, ow = rem & 31;
                const int gk = k0 + c8;
                const int ky = (gk >> 10) & 1, kx = (gk >> 9) & 1, ci = gk & 511;
                gp = A + ((size_t)((b * 64 + 2 * oh + ky) * 64) + (2 * ow + kx)) * 512 + ci;
            } else {
                gp = A + (size_t)(m0 + row) * K + k0 + c8;
            }
            gload_lds16(gp, &As[buf * ABUF + ii * 512]);
        }
        #pragma unroll
        for (int t = 0; t < 2; ++t) {          // stage W tile
            const int ii = wave * 2 + t;
            const int e = ii * 64 + lane;
            const int row = e >> 2, c8 = (e & 3) * 8;
            gload_lds16(Wt + (size_t)(n0 + row) * K + k0 + c8,
                        &Ws[buf * 4096 + ii * 512]);
        }
    };

    stage(0, 0);
    asm volatile("s_waitcnt vmcnt(0)" ::: "memory");
    __builtin_amdgcn_s_barrier();

    for (int it = 0; it < NIT; ++it) {
        const int cur = it & 1;
        if (it + 1 < NIT) stage((it + 1) * 32, cur ^ 1);   // prefetch in flight

        f16x8 af[MT], bf[4];
        #pragma unroll
        for (int mt = 0; mt < MT; ++mt)
            af[mt] = *(const f16x8*)&As[cur * ABUF + (wrow + mt * 16 + l15) * 32 + quad * 8];
        #pragma unroll
        for (int nt = 0; nt < 4; ++nt)
            bf[nt] = *(const f16x8*)&Ws[cur * 4096 + (wn * 64 + nt * 16 + l15) * 32 + quad * 8];
        #pragma unroll
        for (int mt = 0; mt < MT; ++mt)
            #pragma unroll
            for (int nt = 0; nt < 4; ++nt)
                acc[mt][nt] = __builtin_amdgcn_mfma_f32_16x16x32_f16(
                    af[mt], bf[nt], acc[mt][nt], 0, 0, 0);

        asm volatile("s_waitcnt vmcnt(0)" ::: "memory");   // next tile landed
        __builtin_amdgcn_s_barrier();
    }

    // ---- epilogue: C/D layout col=lane&15, row=quad*4+reg ----
    #pragma unroll
    for (int nt = 0; nt < 4; ++nt) {
        const int gcol = n0 + wn * 64 + nt * 16 + l15;
        float bv;
        if (MODE == 6) bv = bias[(gcol & 63) * 8 + (gcol >> 6)];
        else if (MODE == 5) bv = (gcol < 512) ? bias[(gcol & 63) * 8 + (gcol >> 6)]
                                              : bias2[gcol - 512];
        else bv = bias[gcol];
        #pragma unroll
        for (int mt = 0; mt < MT; ++mt) {
            const int row0 = m0 + wrow + mt * 16 + quad * 4;
            if (MODE == 0) {
                #pragma unroll
                for (int r = 0; r < 4; ++r)
                    ((float*)Cv)[(size_t)(row0 + r) * 512 + gcol] = acc[mt][nt][r] + bv;
            } else if (MODE == 4 || MODE == 6) {
                #pragma unroll
                for (int r = 0; r < 4; ++r)
                    ((_Float16*)Cv)[(size_t)(row0 + r) * 512 + gcol] =
                        (_Float16)(acc[mt][nt][r] + bv);
            } else {  // MODE 5
                if (gcol < 512) {
                    #pragma unroll
                    for (int r = 0; r < 4; ++r)
                        ((_Float16*)Cv)[(size_t)(row0 + r) * 512 + gcol] =
                            (_Float16)(acc[mt][nt][r] + bv);
                } else {
                    const int c = gcol - 512;
                    const int h = c & 7, d = c >> 3;
                    const int b_ = row0 >> 10, jj = row0 & 1023;
                    f16x4 o;
                    #pragma unroll
                    for (int r = 0; r < 4; ++r) o[r] = (_Float16)(acc[mt][nt][r] + bv);
                    *(f16x4*)((_Float16*)Cv2 +
                              ((size_t)(b_ * 8 + h) * 64 + d) * 1024 + jj) = o;
                }
            }
        }
    }
}

template<int MODE, bool CONV, int BM>
__global__ __launch_bounds__(256)
void gemm_f16(const _Float16* __restrict__ A, const _Float16* __restrict__ Wt,
              const float* __restrict__ bias, const float* __restrict__ bias2,
              void* __restrict__ Cv, void* __restrict__ Cv2)
{
    __shared__ __align__(16) _Float16 As[2 * BM * 32];
    __shared__ __align__(16) _Float16 Ws[2 * 128 * 32];
    gemm_body<MODE, CONV, BM>(blockIdx.x, blockIdx.y, A, Wt, bias, bias2,
                              Cv, Cv2, As, Ws);
}

// ---------------------------------------------------------------------------
// Fused conv (im2col GEMM, 256 blocks, FIRST: K=2048 long pole) + Q
// projection (512 blocks): both read xh, independent -> one launch (3 blk/CU).
// ---------------------------------------------------------------------------
__global__ __launch_bounds__(256)
void convq_k(const _Float16* __restrict__ xh, const _Float16* __restrict__ srwt,
             const float* __restrict__ srb, const _Float16* __restrict__ wqt,
             const float* __restrict__ bq,
             _Float16* __restrict__ kvh, _Float16* __restrict__ qh)
{
    __shared__ __align__(16) _Float16 As[2 * 128 * 32];
    __shared__ __align__(16) _Float16 Ws[2 * 128 * 32];
    const int id = blockIdx.x;
    if (id < 256) {        // conv: grid (4,64), K=2048
        gemm_body<4, true, 64>(id & 3, id >> 2, xh, srwt, srb, nullptr,
                               kvh, nullptr, As, Ws);
    } else {               // Q proj: grid (4,128)
        const int id2 = id - 256;
        gemm_body<6, false, 128>(id2 & 3, id2 >> 2, xh, wqt, bq, nullptr,
                                 qh, nullptr, As, Ws);
    }
}

// ---------------------------------------------------------------------------
// In-place LayerNorm (fp16 in/out, fp32 stats) over 512 ch; 1 block per row.
// ---------------------------------------------------------------------------
__global__ __launch_bounds__(256)
void ln_k(_Float16* __restrict__ buf, const float* __restrict__ g,
          const float* __restrict__ b)
{
    const int row = blockIdx.x;
    _Float16* p = buf + (size_t)row * 512;
    const int tid = threadIdx.x;
    const float vx = (float)p[tid * 2], vy = (float)p[tid * 2 + 1];
    float s = vx + vy, q = vx * vx + vy * vy;
    #pragma unroll
    for (int off = 32; off > 0; off >>= 1) {
        s += __shfl_xor(s, off);
        q += __shfl_xor(q, off);
    }
    __shared__ float ss[4], sq[4], stat[2];
    const int wid = tid >> 6;
    if ((tid & 63) == 0) { ss[wid] = s; sq[wid] = q; }
    __syncthreads();
    if (tid == 0) {
        const float S = ss[0] + ss[1] + ss[2] + ss[3];
        const float Q = sq[0] + sq[1] + sq[2] + sq[3];
        const float mu = S * (1.f / 512.f);
        const float var = fmaxf(Q * (1.f / 512.f) - mu * mu, 0.f);
        stat[0] = mu;
        stat[1] = rsqrtf(var + 1e-6f);
    }
    __syncthreads();
    const float mu = stat[0], rs = stat[1];
    const float2 gg = *(const float2*)(g + tid * 2);
    const float2 bb = *(const float2*)(b + tid * 2);
    p[tid * 2]     = (_Float16)((vx - mu) * rs * gg.x + bb.x);
    p[tid * 2 + 1] = (_Float16)((vy - mu) * rs * gg.y + bb.y);
}

// ---------------------------------------------------------------------------
// MFMA flash attention v4: 8 waves (512 thr), 512 q-rows per block
// (64 rows per wave as 4 subtiles). Swapped QK^T (mfma(K,Q)) keeps the
// exp'd P tile entirely in registers. K rows are PERMUTED in LDS
// (key k -> row 32*(k>>5) | 16*((k>>2)&1) | 4*((k>>3)&3) | (k&3)) so the
// S^T output chunks ct=2kb,2kb+1 give lane(quad,l15) exactly keys
// kb*32+quad*8+{0..7} for q=l15 -- the A-fragment of a FULL-RATE
// 16x16x32 PV MFMA (the legacy 16x16x16 runs ~4x slower on gfx950).
// V-frags become contiguous b128 reads. Grid (8,32) = 256 blocks.
// q: fp16 [16384][512] (cols h*64+d), k: fp16 [4096][512] (cols h*64+d),
// v: fp16 V^T [bh][64][1024]. 16 key-chunks of 64, single-barrier dbuf.
// Max-free softmax (scores O(1)), deferred l-reduction.
// ---------------------------------------------------------------------------
__global__ __launch_bounds__(512)
void attn_mfma_k(const _Float16* __restrict__ qb,
                 const _Float16* __restrict__ kbuf,
                 const _Float16* __restrict__ vbuf,
                 _Float16* __restrict__ out)
{
    const int bh = blockIdx.y;           // 0..31
    const int qt = blockIdx.x;           // 0..7
    const int b = bh >> 3, h = bh & 7;
    const int tid = threadIdx.x;
    const int wave = tid >> 6, lane = tid & 63;
    const int quad = lane >> 4, l15 = lane & 15;

    __shared__ __align__(16) _Float16 Ks[2][64 * 72];   // [perm'd key][d]
    __shared__ __align__(16) _Float16 Vs[2][64 * 72];   // [d][key]

    // ---- Q frags (B operand), pre-scaled by 0.125*log2(e) ----
    const int qrow = b * 4096 + qt * 512 + wave * 64 + l15;
    const _Float16* qp = qb + (size_t)qrow * 512 + h * 64 + quad * 8;
    f16x8 qf[4][2];
    #pragma unroll
    for (int su = 0; su < 4; ++su) {
        qf[su][0] = *(const f16x8*)(qp + su * 16 * 512);
        qf[su][1] = *(const f16x8*)(qp + su * 16 * 512 + 32);
    }
    {
        const _Float16 qs = (_Float16)0.18033688f;
        #pragma unroll
        for (int su = 0; su < 4; ++su)
            #pragma unroll
            for (int g = 0; g < 2; ++g)
                #pragma unroll
                for (int i = 0; i < 8; ++i) qf[su][g][i] *= qs;
    }

    // ---- staging pointers: 512 thr x 16B = one 64x64 fp16 tile ----
    const int kr = tid >> 3, kc = (tid & 7) * 8;
    // permuted K LDS row: key kr -> row so S^T lands pre-arranged for x32 PV
    const int krp = (kr & 32) | ((kr & 4) << 2) | ((kr >> 1) & 12) | (kr & 3);
    const _Float16* kg = kbuf + (size_t)(b * 1024 + kr) * 512 + h * 64 + kc;
    const _Float16* vg = vbuf + (size_t)(bh * 64 + kr) * 1024 + kc;

    f16x8 krg = *(const f16x8*)kg;
    f16x8 vrg = *(const f16x8*)vg;
    *(f16x8*)&Ks[0][krp * 72 + kc] = krg;
    *(f16x8*)&Vs[0][kr * 72 + kc] = vrg;

    float l_run[4] = {0.f, 0.f, 0.f, 0.f};
    f32x4 acc[4][4] = {};

    for (int kt = 0; kt < 16; ++kt) {
        const int cur = kt & 1;
        __syncthreads();                               // buf[cur] staged, buf[cur^1] free
        if (kt < 15) {                                 // prefetch next chunk
            krg = *(const f16x8*)(kg + (size_t)(kt + 1) * 64 * 512);
            vrg = *(const f16x8*)(vg + (kt + 1) * 64);
        }

        // ---- per 32-key block: swapped QK^T -> exp2 -> x32 PV ----
        #pragma unroll
        for (int kb = 0; kb < 2; ++kb) {
            f16x8 pa[4];                               // P A-frags (8 keys/lane)
            #pragma unroll
            for (int c = 0; c < 2; ++c) {
                const int ct = kb * 2 + c;
                const f16x8 kf0 = *(const f16x8*)&Ks[cur][(ct * 16 + l15) * 72 + quad * 8];
                const f16x8 kf1 = *(const f16x8*)&Ks[cur][(ct * 16 + l15) * 72 + 32 + quad * 8];
                #pragma unroll
                for (int su = 0; su < 4; ++su) {
                    f32x4 s = {};
                    s = __builtin_amdgcn_mfma_f32_16x16x32_f16(kf0, qf[su][0], s, 0, 0, 0);
                    s = __builtin_amdgcn_mfma_f32_16x16x32_f16(kf1, qf[su][1], s, 0, 0, 0);
                    const float p0 = EXP2F(s[0]), p1 = EXP2F(s[1]);
                    const float p2 = EXP2F(s[2]), p3 = EXP2F(s[3]);
                    l_run[su] += (p0 + p1) + (p2 + p3);
                    pa[su][c * 4 + 0] = (_Float16)p0;
                    pa[su][c * 4 + 1] = (_Float16)p1;
                    pa[su][c * 4 + 2] = (_Float16)p2;
                    pa[su][c * 4 + 3] = (_Float16)p3;
                }
            }
            __builtin_amdgcn_s_setprio(1);
            #pragma unroll
            for (int nt = 0; nt < 4; ++nt) {
                const f16x8 vf = *(const f16x8*)&Vs[cur][(nt * 16 + l15) * 72 + kb * 32 + quad * 8];
                #pragma unroll
                for (int su = 0; su < 4; ++su)
                    acc[su][nt] = __builtin_amdgcn_mfma_f32_16x16x32_f16(
                        pa[su], vf, acc[su][nt], 0, 0, 0);
            }
            __builtin_amdgcn_s_setprio(0);
        }

        if (kt < 15) {                                 // write prefetch -> other buf
            *(f16x8*)&Ks[cur ^ 1][krp * 72 + kc] = krg;
            *(f16x8*)&Vs[cur ^ 1][kr * 72 + kc] = vrg;
        }
    }

    // ---- final l reduction (all of a lane's p share q=l15) + epilogue ----
    #pragma unroll
    for (int su = 0; su < 4; ++su) {
        float ts = l_run[su];
        ts += __shfl_xor(ts, 16);
        ts += __shfl_xor(ts, 32);
        float inv[4];
        #pragma unroll
        for (int r = 0; r < 4; ++r)
            inv[r] = 1.0f / __shfl(ts, quad * 4 + r, 16);
        #pragma unroll
        for (int nt = 0; nt < 4; ++nt)
            #pragma unroll
            for (int r = 0; r < 4; ++r) {
                const int row = qt * 512 + wave * 64 + su * 16 + quad * 4 + r;
                const int col = h * 64 + nt * 16 + l15;
                out[((size_t)b * 4096 + row) * 512 + col] =
                    (_Float16)(acc[su][nt][r] * inv[r]);
            }
    }
}

// ---------------------------------------------------------------------------
extern "C" void kernel_launch(void* const* d_in, const int* in_sizes, int n_in,
                              void* d_out, int out_size, void* d_ws, size_t ws_size,
                              hipStream_t stream)
{
    const float* x   = (const float*)d_in[0];
    const float* Wq  = (const float*)d_in[1];
    const float* bq  = (const float*)d_in[2];
    const float* Wk  = (const float*)d_in[3];
    const float* bk  = (const float*)d_in[4];
    const float* Wv  = (const float*)d_in[5];
    const float* bv  = (const float*)d_in[6];
    const float* Wp  = (const float*)d_in[7];
    const float* bp  = (const float*)d_in[8];
    const float* srw = (const float*)d_in[9];
    const float* srb = (const float*)d_in[10];
    const float* lng = (const float*)d_in[11];
    const float* lnb = (const float*)d_in[12];

    _Float16* ws   = (_Float16*)d_ws;
    _Float16* xh   = ws;                    // 8,388,608  (16.8 MB)
    _Float16* atth = xh + 8388608;          // 8,388,608  (16.8 MB)
    _Float16* kvh  = atth + 8388608;        // 2,097,152  (4.2 MB)
    _Float16* kh   = kvh + 2097152;         // 2,097,152  (4.2 MB)
    _Float16* vh   = kh + 2097152;          // 2,097,152  (4.2 MB)
    _Float16* wqt  = vh + 2097152;          // 262,144
    _Float16* wkvt = wqt + 262144;          // 524,288 (Wk perm'd | Wv plain)
    _Float16* wpt  = wkvt + 524288;         // 262,144
    _Float16* srwt = wpt + 262144;          // 1,048,576
    _Float16* qh   = (_Float16*)d_out;      // q scratch in d_out

    // 1. fused prep: cvt + 4x weight transpose + srw transpose
    prep_k<<<6144, 256, 0, stream>>>(x, Wq, Wk, Wv, Wp, srw,
                                     xh, wqt, wkvt, wpt, srwt);
    // 2. fused conv (im2col GEMM, first) + Q projection
    convq_k<<<768, 256, 0, stream>>>(xh, srwt, srb, wqt, bq, kvh, qh);
    // 3. LayerNorm in place
    ln_k<<<4096, 256, 0, stream>>>(kvh, lng, lnb);
    // 4. fused K+V projections (N=1024, BM=64 -> 512 blocks, 2/CU)
    gemm_f16<5, false, 64><<<dim3(8, 64), 256, 0, stream>>>(
        kvh, wkvt, bk, bv, kh, vh);
    // 5. MFMA flash attention (512 q-rows/block, x32 PV via perm'd K rows)
    attn_mfma_k<<<dim3(8, 32), 512, 0, stream>>>(qh, kh, vh, atth);
    // 6. output projection -> d_out fp32
    gemm_f16<0, false, 128><<<dim3(4, 128), 256, 0, stream>>>(
        atth, wpt, bp, nullptr, d_out, nullptr);
}

// Round 5
// 209.683 us; speedup vs baseline: 1.0869x; 1.0869x over previous
//
#include <hip/hip_runtime.h>

// Problem constants (B=4, H=W=64, C=D=512, heads=8, hd=64, SR=2)
// N = 4096 queries, Nk = 1024 keys.

typedef __attribute__((ext_vector_type(8))) _Float16 f16x8;
typedef __attribute__((ext_vector_type(4))) _Float16 f16x4;
typedef __attribute__((ext_vector_type(4))) float f32x4;

#define EXP2F(x) __builtin_amdgcn_exp2f(x)

// async global->LDS, 16B per lane; LDS dest = wave-uniform base + lane*16
__device__ __forceinline__ void gload_lds16(const _Float16* g, _Float16* l)
{
    __builtin_amdgcn_global_load_lds(
        (const __attribute__((address_space(1))) void*)g,
        (__attribute__((address_space(3))) void*)l, 16, 0, 0);
}

template<int N>
__device__ __forceinline__ void wait_vm()
{
    asm volatile("s_waitcnt vmcnt(%0)" :: "n"(N) : "memory");
}

// ---------------------------------------------------------------------------
// Fused prep: blocks [0,4096) x fp32->fp16; [4096,5120) 4x weight transpose;
// [5120,6144) srw transpose. All independent memory-bound work, one launch.
// ---------------------------------------------------------------------------
__global__ __launch_bounds__(256)
void prep_k(const float* __restrict__ x,
            const float* __restrict__ Wq, const float* __restrict__ Wk,
            const float* __restrict__ Wv, const float* __restrict__ Wp,
            const float* __restrict__ srw,
            _Float16* __restrict__ xh, _Float16* __restrict__ wqt,
            _Float16* __restrict__ wkvt, _Float16* __restrict__ wpt,
            _Float16* __restrict__ srwt)
{
    __shared__ float T[32][33];
    const int id = blockIdx.x;
    const int t = threadIdx.x;

    if (id < 4096) {                       // ---- x fp32 -> fp16 ----
        const size_t i = ((size_t)id * 256 + t) * 8;
        const float4 a = *(const float4*)(x + i);
        const float4 b = *(const float4*)(x + i + 4);
        f16x8 o;
        o[0] = (_Float16)a.x; o[1] = (_Float16)a.y; o[2] = (_Float16)a.z; o[3] = (_Float16)a.w;
        o[4] = (_Float16)b.x; o[5] = (_Float16)b.y; o[6] = (_Float16)b.z; o[7] = (_Float16)b.w;
        *(f16x8*)(xh + i) = o;
        return;
    }

    if (id < 5120) {                       // ---- 4x 512x512 transpose ----
        const int id2 = id - 4096;
        const int z = id2 >> 8, k0 = ((id2 >> 4) & 15) * 32, n0 = (id2 & 15) * 32;
        const float* src; _Float16* dst; int perm;
        switch (z) {
            case 0:  src = Wq; dst = wqt;           perm = 1; break;
            case 1:  src = Wk; dst = wkvt;          perm = 1; break;
            case 2:  src = Wv; dst = wkvt + 262144; perm = 0; break;
            default: src = Wp; dst = wpt;           perm = 0; break;
        }
        {
            const int r = t >> 3, c = (t & 7) * 4;
            const float4 v = *(const float4*)(src + (size_t)(k0 + r) * 512 + n0 + c);
            T[r][c + 0] = v.x; T[r][c + 1] = v.y; T[r][c + 2] = v.z; T[r][c + 3] = v.w;
        }
        __syncthreads();
        {
            const int j = t >> 3, i0 = (t & 7) * 4;
            const int n = n0 + j;
            const int nper = perm ? ((n & 7) * 64 + (n >> 3)) : n;
            f16x4 o;
            o[0] = (_Float16)T[i0 + 0][j];
            o[1] = (_Float16)T[i0 + 1][j];
            o[2] = (_Float16)T[i0 + 2][j];
            o[3] = (_Float16)T[i0 + 3][j];
            *(f16x4*)(dst + (size_t)nper * 512 + k0 + i0) = o;
        }
        return;
    }

    {                                      // ---- srw [2048][512] -> [512][2048] ----
        const int id3 = id - 5120;
        const int n0 = (id3 & 15) * 32, k0 = (id3 >> 4) * 32;
        {
            const int r = t >> 3, c = (t & 7) * 4;
            const float4 v = *(const float4*)(srw + (size_t)(k0 + r) * 512 + n0 + c);
            T[r][c + 0] = v.x; T[r][c + 1] = v.y; T[r][c + 2] = v.z; T[r][c + 3] = v.w;
        }
        __syncthreads();
        {
            const int j = t >> 3, i0 = (t & 7) * 4;
            f16x4 o;
            o[0] = (_Float16)T[i0 + 0][j];
            o[1] = (_Float16)T[i0 + 1][j];
            o[2] = (_Float16)T[i0 + 2][j];
            o[3] = (_Float16)T[i0 + 3][j];
            *(f16x4*)(srwt + (size_t)(n0 + j) * 2048 + k0 + i0) = o;
        }
        return;
    }
}

// ---------------------------------------------------------------------------
// fp16 MFMA GEMM body, NBUF-deep pipeline, counted vmcnt, ONE raw barrier
// per K-step (T3+T4). P=NBUF-1 tiles in flight; stage(it+P) is issued right
// after barrier(it) so 2-3 tiles of HBM latency overlap compute.
//   prologue: stage(0..P-1)
//   iter it : vmcnt(min(P-1,rem)*L) ; s_barrier ; stage(it+P) ; ds_read+MFMA
// Reuse race-free: stage(it+P) writes buf (it-1)%NBUF whose readers are all
// past barrier(it). NBUF=4 for BM=64, 3 for BM=128 -> 48KB LDS, 3 blk/CU.
// C[M,128*nx] = A[M,K] @ Wt^T + bias. Wt fp16 [N][K]. BN=128, BK=32.
// 4 waves (2x2): wave tile (BM/2)x64, MT=BM/32 row-tiles x 4 col-tiles.
// MODE: 0 = fp32 row-major [M,512], bias direct
//       4 = fp16 row-major [M,512], bias direct        (conv out)
//       6 = fp16 row-major [M,512], bias head-perm'd    (Q proj)
//       5 = fused KV (N=1024): col<512 -> kh fp16 [4096][512] (perm'd cols);
//           col>=512 -> v^T fp16 [bh][64][1024] batched f16x4 stores
// CONV: A gathered as im2col of 2x2/stride-2 conv on x fp16 (K=2048);
// loop-invariant part of the address chain hoisted (only ky/kx/ci per iter).
// ---------------------------------------------------------------------------
template<int MODE, bool CONV, int BM>
__device__ __forceinline__ void gemm_body(
    const int bx, const int by,
    const _Float16* __restrict__ A, const _Float16* __restrict__ Wt,
    const float* __restrict__ bias, const float* __restrict__ bias2,
    void* __restrict__ Cv, void* __restrict__ Cv2,
    _Float16* __restrict__ As, _Float16* __restrict__ Ws)
{
    constexpr int K = CONV ? 2048 : 512;
    constexpr int NIT = K / 32;
    constexpr int MT = BM / 32;          // row-tiles per wave
    constexpr int AI = BM / 64;          // A staging instrs per wave
    constexpr int ABUF = BM * 32;        // elems per A buffer
    constexpr int NBUF = (BM == 64) ? 4 : 3;
    constexpr int P = NBUF - 1;          // tiles in flight
    constexpr int L = AI + 2;            // loads per stage per wave
    const int tid = threadIdx.x;
    const int wave = tid >> 6, lane = tid & 63;
    const int quad = lane >> 4, l15 = lane & 15;
    const int wm = wave >> 1, wn = wave & 1;
    const int wrow = wm * (BM / 2);
    const int m0 = by * BM, n0 = bx * 128;

    // ---- hoisted staging bases (k-independent) ----
    const _Float16* abase[AI];
    int ac8[AI];
    #pragma unroll
    for (int t = 0; t < AI; ++t) {
        const int e = (wave * AI + t) * 64 + lane;
        const int row = e >> 2, c8 = (e & 3) * 8;
        ac8[t] = c8;
        if (CONV) {
            const int grow = m0 + row;
            const int b = grow >> 10, rem = grow & 1023;
            const int oh = rem >> 5, ow = rem & 31;
            abase[t] = A + ((size_t)((b * 64 + 2 * oh) * 64) + 2 * ow) * 512;
        } else {
            abase[t] = A + (size_t)(m0 + row) * K + c8;
        }
    }
    const _Float16* wbase[2];
    #pragma unroll
    for (int t = 0; t < 2; ++t) {
        const int e = (wave * 2 + t) * 64 + lane;
        const int row = e >> 2, c8 = (e & 3) * 8;
        wbase[t] = Wt + (size_t)(n0 + row) * K + c8;
    }

    auto stage = [&](const int k0, const int buf) {
        #pragma unroll
        for (int t = 0; t < AI; ++t) {
            const _Float16* gp;
            if (CONV) {
                const int gk = k0 + ac8[t];
                gp = abase[t] + ((gk >> 10) & 1) * 32768 + ((gk >> 9) & 1) * 512
                              + (gk & 511);
            } else {
                gp = abase[t] + k0;
            }
            gload_lds16(gp, &As[buf * ABUF + (wave * AI + t) * 512]);
        }
        #pragma unroll
        for (int t = 0; t < 2; ++t)
            gload_lds16(wbase[t] + k0, &Ws[buf * 4096 + (wave * 2 + t) * 512]);
    };

    f32x4 acc[MT][4] = {};

    #pragma unroll
    for (int p = 0; p < P; ++p) stage(p * 32, p);

    int cur = 0, nxt = P % NBUF;
    for (int it = 0; it < NIT; ++it) {
        int rem = NIT - 1 - it;
        if (rem > P - 1) rem = P - 1;
        switch (rem) {                       // tile it landed; newer stay in flight
            case 0:  wait_vm<0>(); break;
            case 1:  wait_vm<L>(); break;
            case 2:  wait_vm<2 * L>(); break;
            default: wait_vm<3 * L>(); break;
        }
        __builtin_amdgcn_s_barrier();
        __builtin_amdgcn_sched_barrier(0);
        if (it + P < NIT) {
            stage((it + P) * 32, nxt);
            nxt = (nxt + 1 == NBUF) ? 0 : nxt + 1;
        }

        f16x8 af[MT], bf[4];
        #pragma unroll
        for (int mt = 0; mt < MT; ++mt)
            af[mt] = *(const f16x8*)&As[cur * ABUF + (wrow + mt * 16 + l15) * 32 + quad * 8];
        #pragma unroll
        for (int nt = 0; nt < 4; ++nt)
            bf[nt] = *(const f16x8*)&Ws[cur * 4096 + (wn * 64 + nt * 16 + l15) * 32 + quad * 8];
        #pragma unroll
        for (int mt = 0; mt < MT; ++mt)
            #pragma unroll
            for (int nt = 0; nt < 4; ++nt)
                acc[mt][nt] = __builtin_amdgcn_mfma_f32_16x16x32_f16(
                    af[mt], bf[nt], acc[mt][nt], 0, 0, 0);

        cur = (cur + 1 == NBUF) ? 0 : cur + 1;
    }

    // ---- epilogue: C/D layout col=lane&15, row=quad*4+reg ----
    #pragma unroll
    for (int nt = 0; nt < 4; ++nt) {
        const int gcol = n0 + wn * 64 + nt * 16 + l15;
        float bv;
        if (MODE == 6) bv = bias[(gcol & 63) * 8 + (gcol >> 6)];
        else if (MODE == 5) bv = (gcol < 512) ? bias[(gcol & 63) * 8 + (gcol >> 6)]
                                              : bias2[gcol - 512];
        else bv = bias[gcol];
        #pragma unroll
        for (int mt = 0; mt < MT; ++mt) {
            const int row0 = m0 + wrow + mt * 16 + quad * 4;
            if (MODE == 0) {
                #pragma unroll
                for (int r = 0; r < 4; ++r)
                    ((float*)Cv)[(size_t)(row0 + r) * 512 + gcol] = acc[mt][nt][r] + bv;
            } else if (MODE == 4 || MODE == 6) {
                #pragma unroll
                for (int r = 0; r < 4; ++r)
                    ((_Float16*)Cv)[(size_t)(row0 + r) * 512 + gcol] =
                        (_Float16)(acc[mt][nt][r] + bv);
            } else {  // MODE 5
                if (gcol < 512) {
                    #pragma unroll
                    for (int r = 0; r < 4; ++r)
                        ((_Float16*)Cv)[(size_t)(row0 + r) * 512 + gcol] =
                            (_Float16)(acc[mt][nt][r] + bv);
                } else {
                    const int c = gcol - 512;
                    const int h = c & 7, d = c >> 3;
                    const int b_ = row0 >> 10, jj = row0 & 1023;
                    f16x4 o;
                    #pragma unroll
                    for (int r = 0; r < 4; ++r) o[r] = (_Float16)(acc[mt][nt][r] + bv);
                    *(f16x4*)((_Float16*)Cv2 +
                              ((size_t)(b_ * 8 + h) * 64 + d) * 1024 + jj) = o;
                }
            }
        }
    }
}

template<int MODE, bool CONV, int BM>
__global__ __launch_bounds__(256)
void gemm_f16(const _Float16* __restrict__ A, const _Float16* __restrict__ Wt,
              const float* __restrict__ bias, const float* __restrict__ bias2,
              void* __restrict__ Cv, void* __restrict__ Cv2)
{
    __shared__ __align__(16) _Float16 lds[24576];   // 48 KB
    constexpr int NBUF = (BM == 64) ? 4 : 3;
    gemm_body<MODE, CONV, BM>(blockIdx.x, blockIdx.y, A, Wt, bias, bias2,
                              Cv, Cv2, lds, lds + NBUF * BM * 32);
}

// ---------------------------------------------------------------------------
// Fused conv (im2col GEMM, 256 blocks, FIRST: K=2048 long pole) + Q
// projection (512 blocks): both read xh, independent -> one launch (3 blk/CU).
// ---------------------------------------------------------------------------
__global__ __launch_bounds__(256)
void convq_k(const _Float16* __restrict__ xh, const _Float16* __restrict__ srwt,
             const float* __restrict__ srb, const _Float16* __restrict__ wqt,
             const float* __restrict__ bq,
             _Float16* __restrict__ kvh, _Float16* __restrict__ qh)
{
    __shared__ __align__(16) _Float16 lds[24576];   // 48 KB
    const int id = blockIdx.x;
    if (id < 256) {        // conv: grid (4,64), K=2048, NBUF=4
        gemm_body<4, true, 64>(id & 3, id >> 2, xh, srwt, srb, nullptr,
                               kvh, nullptr, lds, lds + 4 * 64 * 32);
    } else {               // Q proj: grid (4,128), NBUF=3
        const int id2 = id - 256;
        gemm_body<6, false, 128>(id2 & 3, id2 >> 2, xh, wqt, bq, nullptr,
                                 qh, nullptr, lds, lds + 3 * 128 * 32);
    }
}

// ---------------------------------------------------------------------------
// In-place LayerNorm (fp16 in/out, fp32 stats) over 512 ch; 1 block per row.
// ---------------------------------------------------------------------------
__global__ __launch_bounds__(256)
void ln_k(_Float16* __restrict__ buf, const float* __restrict__ g,
          const float* __restrict__ b)
{
    const int row = blockIdx.x;
    _Float16* p = buf + (size_t)row * 512;
    const int tid = threadIdx.x;
    const float vx = (float)p[tid * 2], vy = (float)p[tid * 2 + 1];
    float s = vx + vy, q = vx * vx + vy * vy;
    #pragma unroll
    for (int off = 32; off > 0; off >>= 1) {
        s += __shfl_xor(s, off);
        q += __shfl_xor(q, off);
    }
    __shared__ float ss[4], sq[4], stat[2];
    const int wid = tid >> 6;
    if ((tid & 63) == 0) { ss[wid] = s; sq[wid] = q; }
    __syncthreads();
    if (tid == 0) {
        const float S = ss[0] + ss[1] + ss[2] + ss[3];
        const float Q = sq[0] + sq[1] + sq[2] + sq[3];
        const float mu = S * (1.f / 512.f);
        const float var = fmaxf(Q * (1.f / 512.f) - mu * mu, 0.f);
        stat[0] = mu;
        stat[1] = rsqrtf(var + 1e-6f);
    }
    __syncthreads();
    const float mu = stat[0], rs = stat[1];
    const float2 gg = *(const float2*)(g + tid * 2);
    const float2 bb = *(const float2*)(b + tid * 2);
    p[tid * 2]     = (_Float16)((vx - mu) * rs * gg.x + bb.x);
    p[tid * 2 + 1] = (_Float16)((vy - mu) * rs * gg.y + bb.y);
}

// ---------------------------------------------------------------------------
// MFMA flash attention v4: 8 waves (512 thr), 512 q-rows per block
// (64 rows per wave as 4 subtiles). Swapped QK^T (mfma(K,Q)) keeps the
// exp'd P tile entirely in registers. K rows are PERMUTED in LDS
// (key k -> row 32*(k>>5) | 16*((k>>2)&1) | 4*((k>>3)&3) | (k&3)) so the
// S^T output chunks ct=2kb,2kb+1 give lane(quad,l15) exactly keys
// kb*32+quad*8+{0..7} for q=l15 -- the A-fragment of a FULL-RATE
// 16x16x32 PV MFMA (the legacy 16x16x16 runs ~4x slower on gfx950).
// V-frags become contiguous b128 reads. Grid (8,32) = 256 blocks.
// q: fp16 [16384][512] (cols h*64+d), k: fp16 [4096][512] (cols h*64+d),
// v: fp16 V^T [bh][64][1024]. 16 key-chunks of 64, single-barrier dbuf.
// Max-free softmax (scores O(1)), deferred l-reduction.
// ---------------------------------------------------------------------------
__global__ __launch_bounds__(512)
void attn_mfma_k(const _Float16* __restrict__ qb,
                 const _Float16* __restrict__ kbuf,
                 const _Float16* __restrict__ vbuf,
                 _Float16* __restrict__ out)
{
    const int bh = blockIdx.y;           // 0..31
    const int qt = blockIdx.x;           // 0..7
    const int b = bh >> 3, h = bh & 7;
    const int tid = threadIdx.x;
    const int wave = tid >> 6, lane = tid & 63;
    const int quad = lane >> 4, l15 = lane & 15;

    __shared__ __align__(16) _Float16 Ks[2][64 * 72];   // [perm'd key][d]
    __shared__ __align__(16) _Float16 Vs[2][64 * 72];   // [d][key]

    // ---- Q frags (B operand), pre-scaled by 0.125*log2(e) ----
    const int qrow = b * 4096 + qt * 512 + wave * 64 + l15;
    const _Float16* qp = qb + (size_t)qrow * 512 + h * 64 + quad * 8;
    f16x8 qf[4][2];
    #pragma unroll
    for (int su = 0; su < 4; ++su) {
        qf[su][0] = *(const f16x8*)(qp + su * 16 * 512);
        qf[su][1] = *(const f16x8*)(qp + su * 16 * 512 + 32);
    }
    {
        const _Float16 qs = (_Float16)0.18033688f;
        #pragma unroll
        for (int su = 0; su < 4; ++su)
            #pragma unroll
            for (int g = 0; g < 2; ++g)
                #pragma unroll
                for (int i = 0; i < 8; ++i) qf[su][g][i] *= qs;
    }

    // ---- staging pointers: 512 thr x 16B = one 64x64 fp16 tile ----
    const int kr = tid >> 3, kc = (tid & 7) * 8;
    // permuted K LDS row: key kr -> row so S^T lands pre-arranged for x32 PV
    const int krp = (kr & 32) | ((kr & 4) << 2) | ((kr >> 1) & 12) | (kr & 3);
    const _Float16* kg = kbuf + (size_t)(b * 1024 + kr) * 512 + h * 64 + kc;
    const _Float16* vg = vbuf + (size_t)(bh * 64 + kr) * 1024 + kc;

    f16x8 krg = *(const f16x8*)kg;
    f16x8 vrg = *(const f16x8*)vg;
    *(f16x8*)&Ks[0][krp * 72 + kc] = krg;
    *(f16x8*)&Vs[0][kr * 72 + kc] = vrg;

    float l_run[4] = {0.f, 0.f, 0.f, 0.f};
    f32x4 acc[4][4] = {};

    for (int kt = 0; kt < 16; ++kt) {
        const int cur = kt & 1;
        __syncthreads();                               // buf[cur] staged, buf[cur^1] free
        if (kt < 15) {                                 // prefetch next chunk
            krg = *(const f16x8*)(kg + (size_t)(kt + 1) * 64 * 512);
            vrg = *(const f16x8*)(vg + (kt + 1) * 64);
        }

        // ---- per 32-key block: swapped QK^T -> exp2 -> x32 PV ----
        #pragma unroll
        for (int kb = 0; kb < 2; ++kb) {
            f16x8 pa[4];                               // P A-frags (8 keys/lane)
            #pragma unroll
            for (int c = 0; c < 2; ++c) {
                const int ct = kb * 2 + c;
                const f16x8 kf0 = *(const f16x8*)&Ks[cur][(ct * 16 + l15) * 72 + quad * 8];
                const f16x8 kf1 = *(const f16x8*)&Ks[cur][(ct * 16 + l15) * 72 + 32 + quad * 8];
                #pragma unroll
                for (int su = 0; su < 4; ++su) {
                    f32x4 s = {};
                    s = __builtin_amdgcn_mfma_f32_16x16x32_f16(kf0, qf[su][0], s, 0, 0, 0);
                    s = __builtin_amdgcn_mfma_f32_16x16x32_f16(kf1, qf[su][1], s, 0, 0, 0);
                    const float p0 = EXP2F(s[0]), p1 = EXP2F(s[1]);
                    const float p2 = EXP2F(s[2]), p3 = EXP2F(s[3]);
                    l_run[su] += (p0 + p1) + (p2 + p3);
                    pa[su][c * 4 + 0] = (_Float16)p0;
                    pa[su][c * 4 + 1] = (_Float16)p1;
                    pa[su][c * 4 + 2] = (_Float16)p2;
                    pa[su][c * 4 + 3] = (_Float16)p3;
                }
            }
            __builtin_amdgcn_s_setprio(1);
            #pragma unroll
            for (int nt = 0; nt < 4; ++nt) {
                const f16x8 vf = *(const f16x8*)&Vs[cur][(nt * 16 + l15) * 72 + kb * 32 + quad * 8];
                #pragma unroll
                for (int su = 0; su < 4; ++su)
                    acc[su][nt] = __builtin_amdgcn_mfma_f32_16x16x32_f16(
                        pa[su], vf, acc[su][nt], 0, 0, 0);
            }
            __builtin_amdgcn_s_setprio(0);
        }

        if (kt < 15) {                                 // write prefetch -> other buf
            *(f16x8*)&Ks[cur ^ 1][krp * 72 + kc] = krg;
            *(f16x8*)&Vs[cur ^ 1][kr * 72 + kc] = vrg;
        }
    }

    // ---- final l reduction (all of a lane's p share q=l15) + epilogue ----
    #pragma unroll
    for (int su = 0; su < 4; ++su) {
        float ts = l_run[su];
        ts += __shfl_xor(ts, 16);
        ts += __shfl_xor(ts, 32);
        float inv[4];
        #pragma unroll
        for (int r = 0; r < 4; ++r)
            inv[r] = 1.0f / __shfl(ts, quad * 4 + r, 16);
        #pragma unroll
        for (int nt = 0; nt < 4; ++nt)
            #pragma unroll
            for (int r = 0; r < 4; ++r) {
                const int row = qt * 512 + wave * 64 + su * 16 + quad * 4 + r;
                const int col = h * 64 + nt * 16 + l15;
                out[((size_t)b * 4096 + row) * 512 + col] =
                    (_Float16)(acc[su][nt][r] * inv[r]);
            }
    }
}

// ---------------------------------------------------------------------------
extern "C" void kernel_launch(void* const* d_in, const int* in_sizes, int n_in,
                              void* d_out, int out_size, void* d_ws, size_t ws_size,
                              hipStream_t stream)
{
    const float* x   = (const float*)d_in[0];
    const float* Wq  = (const float*)d_in[1];
    const float* bq  = (const float*)d_in[2];
    const float* Wk  = (const float*)d_in[3];
    const float* bk  = (const float*)d_in[4];
    const float* Wv  = (const float*)d_in[5];
    const float* bv  = (const float*)d_in[6];
    const float* Wp  = (const float*)d_in[7];
    const float* bp  = (const float*)d_in[8];
    const float* srw = (const float*)d_in[9];
    const float* srb = (const float*)d_in[10];
    const float* lng = (const float*)d_in[11];
    const float* lnb = (const float*)d_in[12];

    _Float16* ws   = (_Float16*)d_ws;
    _Float16* xh   = ws;                    // 8,388,608  (16.8 MB)
    _Float16* atth = xh + 8388608;          // 8,388,608  (16.8 MB)
    _Float16* kvh  = atth + 8388608;        // 2,097,152  (4.2 MB)
    _Float16* kh   = kvh + 2097152;         // 2,097,152  (4.2 MB)
    _Float16* vh   = kh + 2097152;          // 2,097,152  (4.2 MB)
    _Float16* wqt  = vh + 2097152;          // 262,144
    _Float16* wkvt = wqt + 262144;          // 524,288 (Wk perm'd | Wv plain)
    _Float16* wpt  = wkvt + 524288;         // 262,144
    _Float16* srwt = wpt + 262144;          // 1,048,576
    _Float16* qh   = (_Float16*)d_out;      // q scratch in d_out

    // 1. fused prep: cvt + 4x weight transpose + srw transpose
    prep_k<<<6144, 256, 0, stream>>>(x, Wq, Wk, Wv, Wp, srw,
                                     xh, wqt, wkvt, wpt, srwt);
    // 2. fused conv (im2col GEMM, first) + Q projection
    convq_k<<<768, 256, 0, stream>>>(xh, srwt, srb, wqt, bq, kvh, qh);
    // 3. LayerNorm in place
    ln_k<<<4096, 256, 0, stream>>>(kvh, lng, lnb);
    // 4. fused K+V projections (N=1024, BM=64 -> 512 blocks, NBUF=4)
    gemm_f16<5, false, 64><<<dim3(8, 64), 256, 0, stream>>>(
        kvh, wkvt, bk, bv, kh, vh);
    // 5. MFMA flash attention (512 q-rows/block, x32 PV via perm'd K rows)
    attn_mfma_k<<<dim3(8, 32), 512, 0, stream>>>(qh, kh, vh, atth);
    // 6. output projection -> d_out fp32
    gemm_f16<0, false, 128><<<dim3(4, 128), 256, 0, stream>>>(
        atth, wpt, bp, nullptr, d_out, nullptr);
}